// Round 6
// baseline (182.270 us; speedup 1.0000x reference)
//
#include <hip/hip_runtime.h>

#define DEV __device__ __forceinline__

typedef __attribute__((ext_vector_type(8))) short bf16x8;
typedef __attribute__((ext_vector_type(4))) float f32x4;
typedef __attribute__((ext_vector_type(16))) float f32x16;

// ---------- helpers ----------
DEV ushort f2bf(float f) {
  union { float f; unsigned u; } x; x.f = f;
  unsigned r = (x.u + 0x7FFFu + ((x.u >> 16) & 1u)) >> 16;
  return (ushort)r;
}

DEV void gload16(const void* g, void* l) {
  __builtin_amdgcn_global_load_lds(
      (const __attribute__((address_space(1))) void*)g,
      (__attribute__((address_space(3))) void*)l, 16, 0, 0);
}

DEV f32x4 mfma16(bf16x8 a, bf16x8 b, f32x4 c) {
  return __builtin_amdgcn_mfma_f32_16x16x32_bf16(a, b, c, 0, 0, 0);
}
DEV f32x16 mfma32(bf16x8 a, bf16x8 b, f32x16 c) {
  return __builtin_amdgcn_mfma_f32_32x32x16_bf16(a, b, c, 0, 0, 0);
}

DEV unsigned cvtpk(float a, float b) {
  unsigned r;
  asm("v_cvt_pk_bf16_f32 %0, %1, %2" : "=v"(r) : "v"(a), "v"(b));
  return r;
}

#if __has_builtin(__builtin_amdgcn_exp2f)
#define EXP2(x) __builtin_amdgcn_exp2f(x)
#else
#define EXP2(x) exp2f(x)
#endif

// ---------- sizes ----------
#define BB 2
#define SS 2048
#define HH 16
#define DD 64
#define DM 1024
#define MROWS (BB * SS)       // 4096
#define NQKV  (3 * DM)        // 3072
#define NQK   (2 * DM)        // 2048 (Q|K buffer stride)

// ---------- convert & pack f32 -> bf16 ----------
__global__ void convert_kernel(const float* __restrict__ hs,
                               const float* __restrict__ Wq, const float* __restrict__ bq,
                               const float* __restrict__ Wk, const float* __restrict__ bk,
                               const float* __restrict__ Wv, const float* __restrict__ bv,
                               const float* __restrict__ Wy,
                               ushort* __restrict__ Xb, ushort* __restrict__ Wqkv,
                               ushort* __restrict__ Wyb, float* __restrict__ bqkv) {
  const int HS_V = (MROWS * DM) / 4;     // 1048576
  const int WQ_V = (NQKV * DM) / 4;      // 786432
  const int WY_V = (DM * DM) / 4;        // 262144
  int idx = blockIdx.x * 256 + threadIdx.x;
  if (idx < HS_V) {
    float4 v = ((const float4*)hs)[idx];
    ushort4 o; o.x = f2bf(v.x); o.y = f2bf(v.y); o.z = f2bf(v.z); o.w = f2bf(v.w);
    ((ushort4*)Xb)[idx] = o;
  } else if (idx < HS_V + WQ_V) {
    int e = (idx - HS_V) * 4;
    int n = e >> 10, k = e & 1023;
    const float* W = (n < 1024) ? Wq : (n < 2048) ? Wk : Wv;
    int nn = n & 1023;
    float4 v = *(const float4*)(W + nn * 1024 + k);
    ushort4 o; o.x = f2bf(v.x); o.y = f2bf(v.y); o.z = f2bf(v.z); o.w = f2bf(v.w);
    ((ushort4*)Wqkv)[idx - HS_V] = o;
  } else if (idx < HS_V + WQ_V + WY_V) {
    int e = idx - HS_V - WQ_V;
    float4 v = ((const float4*)Wy)[e];
    ushort4 o; o.x = f2bf(v.x); o.y = f2bf(v.y); o.z = f2bf(v.z); o.w = f2bf(v.w);
    ((ushort4*)Wyb)[e] = o;
  }
  if (idx < NQKV)
    bqkv[idx] = (idx < 1024) ? bq[idx] : (idx < 2048) ? bk[idx - 1024] : bv[idx - 2048];
}

// ---------- GEMM, async 2-phase pipeline (T3 minimal, race-free ledger) ----------
// Per K-tile t: [barrier; (t+2<nt)? STAGE(slot p, t+2); MFMA(tile t, regs);
//   (t+2<nt)? vmcnt(LOADS) : vmcnt(0); barrier; ds_read(tile t+1 -> regs); lgkmcnt(0)]
// Counted vmcnt leaves ONLY t+2's loads in flight => tile t+1 landed before read.
// Tail fix (round-5 race): when no prefetch was issued, vmcnt(LOADS) is a no-op,
// so the else-arm drains vmcnt(0) before reading tile t+1.
template <int BM, bool OUT_F32, bool VSPLIT>
__global__ void gemm_bt(const ushort* __restrict__ A, const ushort* __restrict__ Bw,
                        const float* __restrict__ bias, void* __restrict__ Cout,
                        ushort* __restrict__ VtOut,
                        int M, int N, int K, int Nc, int scaleN, float qscale) {
  constexpr int NI = BM / 32;            // A-frags per wave (m dir)
  constexpr int ASTEPS = BM / 32;        // staging steps for A (256 thr, 16B each)
  constexpr int LOADS = ASTEPS + 4;      // gloads per thread per K-tile
  constexpr int SLOT = (BM + 128) * 128; // bytes per LDS slot (A then B), BK=64
  __shared__ __align__(16) char GL[2 * SLOT];

  const int tid = threadIdx.x;
  const int lane = tid & 63;
  const int wave = tid >> 6;
  const int lg = lane >> 4, l15 = lane & 15;
  const int m0 = blockIdx.x * BM, n0 = blockIdx.y * 128;
  const int wm = (wave >> 1) * (BM / 2), wn = (wave & 1) * 64;

  f32x4 acc[NI][4] = {};
  bf16x8 af[NI][2], bfr[4][2];

  const int srow = tid >> 3;
  const int scs = (tid & 7) ^ (srow & 7);

#define STAGE(p_, k0_) do {                                              \
    _Pragma("unroll")                                                    \
    for (int s_ = 0; s_ < ASTEPS; ++s_)                                  \
      gload16(A + (size_t)(m0 + srow + s_ * 32) * K + (k0_) + scs * 8,   \
              GL + (p_) * SLOT + (tid + s_ * 256) * 16);                 \
    _Pragma("unroll")                                                    \
    for (int s_ = 0; s_ < 4; ++s_)                                       \
      gload16(Bw + (size_t)(n0 + srow + s_ * 32) * K + (k0_) + scs * 8,  \
              GL + (p_) * SLOT + BM * 128 + (tid + s_ * 256) * 16);      \
  } while (0)

#define LOADFRAGS(p_) do {                                               \
    const char* Ab_ = GL + (p_) * SLOT;                                  \
    const char* Bb_ = Ab_ + BM * 128;                                    \
    _Pragma("unroll")                                                    \
    for (int kk_ = 0; kk_ < 2; ++kk_) {                                  \
      _Pragma("unroll")                                                  \
      for (int i_ = 0; i_ < NI; ++i_) {                                  \
        int rA_ = wm + i_ * 16 + l15;                                    \
        int cA_ = (kk_ * 4 + lg) ^ (rA_ & 7);                            \
        af[i_][kk_] = *(const bf16x8*)(Ab_ + rA_ * 128 + cA_ * 16);      \
      }                                                                  \
      _Pragma("unroll")                                                  \
      for (int j_ = 0; j_ < 4; ++j_) {                                   \
        int rB_ = wn + j_ * 16 + l15;                                    \
        int cB_ = (kk_ * 4 + lg) ^ (rB_ & 7);                            \
        bfr[j_][kk_] = *(const bf16x8*)(Bb_ + rB_ * 128 + cB_ * 16);     \
      }                                                                  \
    }                                                                    \
  } while (0)

#define VMCNT_L() do {                                                   \
    if constexpr (LOADS == 8) asm volatile("s_waitcnt vmcnt(8)" ::: "memory"); \
    else asm volatile("s_waitcnt vmcnt(6)" ::: "memory");                \
  } while (0)
#define VMCNT_0() asm volatile("s_waitcnt vmcnt(0)" ::: "memory")

  const int nt = K >> 6;
  int p = 0;

  // prologue: stage tiles 0 and 1, confirm tile 0, preload its fragments
  STAGE(0, 0);
  if (nt > 1) { STAGE(1, 64); VMCNT_L(); } else { VMCNT_0(); }
  __builtin_amdgcn_s_barrier();
  __builtin_amdgcn_sched_barrier(0);
  LOADFRAGS(0);
  asm volatile("s_waitcnt lgkmcnt(0)" ::: "memory");
  __builtin_amdgcn_sched_barrier(0);

#pragma unroll 1
  for (int t = 0; t < nt; ++t) {
    __builtin_amdgcn_s_barrier();        // all waves done reading slot p
    __builtin_amdgcn_sched_barrier(0);
    const bool pre = (t + 2 < nt);
    if (pre) STAGE(p, (t + 2) << 6);
#pragma unroll
    for (int kk = 0; kk < 2; ++kk)
#pragma unroll
      for (int i = 0; i < NI; ++i)
#pragma unroll
        for (int j = 0; j < 4; ++j)
          acc[i][j] = mfma16(af[i][kk], bfr[j][kk], acc[i][j]);
    if (pre) VMCNT_L();                   // tile t+1 landed (only t+2's in flight)
    else VMCNT_0();                       // tail: drain tile t+1 (round-5 race fix)
    __builtin_amdgcn_s_barrier();
    __builtin_amdgcn_sched_barrier(0);
    if (t + 1 < nt) {
      LOADFRAGS(p ^ 1);
      asm volatile("s_waitcnt lgkmcnt(0)" ::: "memory");
      __builtin_amdgcn_sched_barrier(0);
    }
    p ^= 1;
  }

  // epilogue
  if (VSPLIT && n0 >= 2048) {
    // V quarter: write directly into Vt [b*16+h][d][s] (transpose fused)
#pragma unroll
    for (int i = 0; i < NI; ++i) {
#pragma unroll
      for (int j = 0; j < 4; ++j) {
        int n = n0 + wn + j * 16 + l15;
        float bv = bias[n];
        int h = (n >> 6) & 15, d = n & 63;
        int mb = m0 + wm + i * 16 + lg * 4;
        int b = mb >> 11, s = mb & 2047;
        ushort4 o;
        o.x = f2bf(acc[i][j][0] + bv);
        o.y = f2bf(acc[i][j][1] + bv);
        o.z = f2bf(acc[i][j][2] + bv);
        o.w = f2bf(acc[i][j][3] + bv);
        *(ushort4*)(VtOut + ((size_t)(b * 16 + h) * 64 + d) * SS + s) = o;
      }
    }
  } else {
#pragma unroll
    for (int i = 0; i < NI; ++i) {
#pragma unroll
      for (int j = 0; j < 4; ++j) {
        int n = n0 + wn + j * 16 + l15;
        float bv = bias[n];
        float qs = (n < scaleN) ? qscale : 1.0f;
#pragma unroll
        for (int r = 0; r < 4; ++r) {
          int m = m0 + wm + i * 16 + lg * 4 + r;
          float v = (acc[i][j][r] + bv) * qs;
          if (OUT_F32)
            ((float*)Cout)[(size_t)m * Nc + n] = v;
          else
            ((ushort*)Cout)[(size_t)m * Nc + n] = f2bf(v);
        }
      }
    }
  }
#undef STAGE
#undef LOADFRAGS
#undef VMCNT_L
#undef VMCNT_0
}

// ---------- flash attention: split-K groups + sequential qtile pairing ----------
// grid 512 x 256thr = 4 waves. QBLK=64 (waves 0/1 = q halves), groups {w0,w1},{w2,w3}
// process even/odd KV blocks (KVBLK=64) with private double-buffers; partials
// (o_acc, psum) merged via LDS (valid: reference softmax has no max-subtraction,
// so partials are pure sums). Qtile pair {x, 31-x} => every block ~17 iters flat.
__global__ __launch_bounds__(256, 2)
void attn_kernel(const ushort* __restrict__ QK, const ushort* __restrict__ Vt,
                 ushort* __restrict__ Ob) {
  __shared__ __align__(16) char SMEM[65536];

  const int tid = threadIdx.x;
  const int wave = tid >> 6, lane = tid & 63;
  const int l31 = lane & 31, hi = lane >> 5;
  const int grp = wave >> 1, wq = wave & 1;

  // XCD-locality swizzle: bh&7 == n&7 => each XCD sees 4 bh (KV fits L2)
  const int n = blockIdx.x;
  const int bh = (n & 7) | ((n >> 7) << 3);
  const int pairi = (n >> 3) & 15;
  const int b = bh >> 4, h = bh & 15;

  // probe v_permlane32_swap direction (wave-uniform)
  int px = lane, pw = 1000;
  asm volatile("v_permlane32_swap_b32 %0, %1" : "+v"(px), "+v"(pw));
  const bool defA = (__builtin_amdgcn_readfirstlane(px) == 0);

  const int gtid = tid & 127;
  const int srow = gtid >> 3;
  const int scs = (gtid & 7) ^ (srow & 7);
  const ushort* Kg = QK + (size_t)(b * SS + srow) * NQK + DM + h * 64 + scs * 8;
  const ushort* Vg = Vt + (size_t)(bh * 64 + srow) * SS + scs * 8;

#define STAGE(d_, kv0_) do {                                            \
    const ushort* kg_ = Kg + (size_t)(kv0_) * NQK;                      \
    const ushort* vg_ = Vg + (kv0_);                                    \
    char* kl_ = SMEM + (grp * 2 + (d_)) * 8192 + gtid * 16;             \
    char* vl_ = SMEM + 32768 + (grp * 2 + (d_)) * 8192 + gtid * 16;     \
    _Pragma("unroll")                                                   \
    for (int s_ = 0; s_ < 4; ++s_) {                                    \
      gload16(kg_ + (size_t)s_ * 16 * NQK, kl_ + s_ * 2048);            \
      gload16(vg_ + (size_t)s_ * 16 * SS,  vl_ + s_ * 2048);            \
    }                                                                   \
  } while (0)

  union U4 { unsigned u[4]; bf16x8 v; };

#define PACKH(sv, R, D0, D1, D2, D3) do {                              \
    unsigned X = cvtpk(sv[R + 0], sv[R + 1]);                          \
    unsigned Y = cvtpk(sv[R + 2], sv[R + 3]);                          \
    unsigned W = cvtpk(sv[R + 4], sv[R + 5]);                          \
    unsigned Z = cvtpk(sv[R + 6], sv[R + 7]);                          \
    if (defA) {                                                        \
      asm volatile("v_permlane32_swap_b32 %0, %1" : "+v"(X), "+v"(W)); \
      asm volatile("v_permlane32_swap_b32 %0, %1" : "+v"(Y), "+v"(Z)); \
    } else {                                                           \
      asm volatile("v_permlane32_swap_b32 %0, %1" : "+v"(W), "+v"(X)); \
      asm volatile("v_permlane32_swap_b32 %0, %1" : "+v"(Z), "+v"(Y)); \
    }                                                                  \
    D0 = X; D1 = Y; D2 = W; D3 = Z;                                    \
  } while (0)

#pragma unroll 1
  for (int ph = 0; ph < 2; ++ph) {
    __builtin_amdgcn_s_barrier();  // protects merge area of previous phase

    const int qt = ph ? (31 - pairi) : pairi;
    const int q0 = qt * 64;
    const int nkv = qt + 1;
    const int niter = (nkv + 1) >> 1;
    const int qw = q0 + wq * 32;
    const int q_lane = qw + l31;

    const ushort* Qrow = QK + (size_t)(b * SS + q_lane) * NQK + h * 64 + hi * 8;
    bf16x8 qf0 = *(const bf16x8*)(Qrow);
    bf16x8 qf1 = *(const bf16x8*)(Qrow + 16);
    bf16x8 qf2 = *(const bf16x8*)(Qrow + 32);
    bf16x8 qf3 = *(const bf16x8*)(Qrow + 48);

    f32x16 acc0 = {}, acc1 = {};
    float ps0 = 0.f, ps1 = 0.f, ps2 = 0.f, ps3 = 0.f;

    if (grp < nkv) STAGE(0, grp * 64);
    int buf = 0;

#pragma unroll 1
    for (int it = 0; it < niter; ++it) {
      const int j = 2 * it + grp;
      if (j + 2 < nkv) {
        STAGE(buf ^ 1, (j + 2) * 64);
        asm volatile("s_waitcnt vmcnt(8)" ::: "memory");
      } else {
        asm volatile("s_waitcnt vmcnt(0)" ::: "memory");
      }
      __builtin_amdgcn_s_barrier();
      __builtin_amdgcn_sched_barrier(0);

      if (j < nkv) {
        const int kv0 = j * 64;
        const char* Kb = SMEM + (grp * 2 + buf) * 8192;
        const char* Vb = SMEM + 32768 + (grp * 2 + buf) * 8192;

        f32x16 s0 = {}, s1 = {};
        __builtin_amdgcn_s_setprio(1);
#pragma unroll
        for (int ks = 0; ks < 4; ++ks) {
          const int ch = (((ks * 2 + hi) ^ (l31 & 7)) * 16);
          bf16x8 kfa = *(const bf16x8*)(Kb + l31 * 128 + ch);
          bf16x8 kfb = *(const bf16x8*)(Kb + (l31 + 32) * 128 + ch);
          bf16x8 qk = (ks == 0) ? qf0 : (ks == 1) ? qf1 : (ks == 2) ? qf2 : qf3;
          s0 = mfma32(kfa, qk, s0);
          s1 = mfma32(kfb, qk, s1);
        }
        __builtin_amdgcn_s_setprio(0);

        if (j == qt) {
#pragma unroll
          for (int r = 0; r < 16; ++r) {
            const int tb = (r & 3) + 8 * (r >> 2) + 4 * hi;
            if (kv0 + tb > q_lane) s0[r] = -1e30f;
            if (kv0 + 32 + tb > q_lane) s1[r] = -1e30f;
          }
        }

#pragma unroll
        for (int r = 0; r < 16; r += 4) {
          float a0 = EXP2(s0[r]), a1 = EXP2(s0[r + 1]), a2 = EXP2(s0[r + 2]), a3 = EXP2(s0[r + 3]);
          s0[r] = a0; s0[r + 1] = a1; s0[r + 2] = a2; s0[r + 3] = a3;
          ps0 += a0; ps1 += a1; ps2 += a2; ps3 += a3;
          float b0 = EXP2(s1[r]), b1 = EXP2(s1[r + 1]), b2 = EXP2(s1[r + 2]), b3 = EXP2(s1[r + 3]);
          s1[r] = b0; s1[r + 1] = b1; s1[r + 2] = b2; s1[r + 3] = b3;
          ps0 += b0; ps1 += b1; ps2 += b2; ps3 += b3;
        }

        U4 f0, f1, f2, f3;
        PACKH(s0, 0, f0.u[0], f0.u[1], f0.u[2], f0.u[3]);
        PACKH(s0, 8, f1.u[0], f1.u[1], f1.u[2], f1.u[3]);
        PACKH(s1, 0, f2.u[0], f2.u[1], f2.u[2], f2.u[3]);
        PACKH(s1, 8, f3.u[0], f3.u[1], f3.u[2], f3.u[3]);

        __builtin_amdgcn_s_setprio(1);
#pragma unroll
        for (int ts = 0; ts < 4; ++ts) {
          const int ch = (((ts * 2 + hi) ^ (l31 & 7)) * 16);
          bf16x8 vfa = *(const bf16x8*)(Vb + l31 * 128 + ch);
          bf16x8 vfb = *(const bf16x8*)(Vb + (l31 + 32) * 128 + ch);
          bf16x8 pf = (ts == 0) ? f0.v : (ts == 1) ? f1.v : (ts == 2) ? f2.v : f3.v;
          acc0 = mfma32(vfa, pf, acc0);
          acc1 = mfma32(vfb, pf, acc1);
        }
        __builtin_amdgcn_s_setprio(0);
      }
      __builtin_amdgcn_sched_barrier(0);
      __builtin_amdgcn_s_barrier();
      buf ^= 1;
    }

    // ---- merge group partials (pure sums; no rescale needed) ----
    float psum = ps0 + ps1 + ps2 + ps3;
    f32x4* MA = (f32x4*)SMEM;            // [8][128]
    float* MP = (float*)(SMEM + 32768);  // [128]
    const int slot = wq * 64 + lane;
    if (grp == 1) {
#pragma unroll
      for (int c = 0; c < 4; ++c) {
        f32x4 t0 = {acc0[4 * c], acc0[4 * c + 1], acc0[4 * c + 2], acc0[4 * c + 3]};
        MA[c * 128 + slot] = t0;
        f32x4 t1 = {acc1[4 * c], acc1[4 * c + 1], acc1[4 * c + 2], acc1[4 * c + 3]};
        MA[(c + 4) * 128 + slot] = t1;
      }
      MP[slot] = psum;
    }
    __builtin_amdgcn_s_barrier();
    if (grp == 0) {
#pragma unroll
      for (int c = 0; c < 4; ++c) {
        f32x4 t0 = MA[c * 128 + slot];
        f32x4 t1 = MA[(c + 4) * 128 + slot];
        acc0[4 * c] += t0[0]; acc0[4 * c + 1] += t0[1];
        acc0[4 * c + 2] += t0[2]; acc0[4 * c + 3] += t0[3];
        acc1[4 * c] += t1[0]; acc1[4 * c + 1] += t1[1];
        acc1[4 * c + 2] += t1[2]; acc1[4 * c + 3] += t1[3];
      }
      psum += MP[slot];
      float tot = psum + __shfl_xor(psum, 32, 64);
      float inv = 1.0f / tot;
      ushort* orow = Ob + (size_t)(b * SS + q_lane) * DM + h * 64;
#pragma unroll
      for (int g = 0; g < 4; ++g) {
        uint2 st;
        st.x = cvtpk(acc0[4 * g + 0] * inv, acc0[4 * g + 1] * inv);
        st.y = cvtpk(acc0[4 * g + 2] * inv, acc0[4 * g + 3] * inv);
        *(uint2*)(orow + 8 * g + 4 * hi) = st;
        uint2 st2;
        st2.x = cvtpk(acc1[4 * g + 0] * inv, acc1[4 * g + 1] * inv);
        st2.y = cvtpk(acc1[4 * g + 2] * inv, acc1[4 * g + 3] * inv);
        *(uint2*)(orow + 32 + 8 * g + 4 * hi) = st2;
      }
    }
  }
#undef STAGE
#undef PACKH
}

// ---------- launch ----------
extern "C" void kernel_launch(void* const* d_in, const int* in_sizes, int n_in,
                              void* d_out, int out_size, void* d_ws, size_t ws_size,
                              hipStream_t stream) {
  const float* hs = (const float*)d_in[0];
  const float* Wq = (const float*)d_in[1];
  const float* bq = (const float*)d_in[2];
  const float* Wk = (const float*)d_in[3];
  const float* bk = (const float*)d_in[4];
  const float* Wv = (const float*)d_in[5];
  const float* bv = (const float*)d_in[6];
  const float* Wy = (const float*)d_in[7];
  const float* by = (const float*)d_in[8];
  float* out = (float*)d_out;

  char* ws = (char*)d_ws;
  ushort* Xb   = (ushort*)(ws);                          // 8 MiB  [4096][1024]
  ushort* Wqkv = (ushort*)(ws + (8ull  << 20));          // 6 MiB  [3072][1024]
  ushort* Wyb  = (ushort*)(ws + (14ull << 20));          // 2 MiB  [1024][1024]
  float*  bqkv = (float*) (ws + (16ull << 20));          // 12 KiB
  ushort* QK   = (ushort*)(ws + (17ull << 20));          // 16 MiB [4096][2048]
  ushort* Vt   = (ushort*)(ws + (33ull << 20));          // 8 MiB  [32][64][2048]
  ushort* Ob   = (ushort*)(ws + (41ull << 20));          // 8 MiB  [4096][1024]

  const float QSC = 0.125f * 1.44269504088896f;  // 1/sqrt(D) * log2(e)

  convert_kernel<<<dim3(8192), dim3(256), 0, stream>>>(hs, Wq, bq, Wk, bk, Wv, bv, Wy,
                                                       Xb, Wqkv, Wyb, bqkv);
  // QKV projection: Q|K -> QK buffer (stride 2048), V -> Vt (transpose fused)
  gemm_bt<128, false, true><<<dim3(32, 24), dim3(256), 0, stream>>>(
      Xb, Wqkv, bqkv, QK, Vt, MROWS, NQKV, DM, NQK, 1024, QSC);
  attn_kernel<<<dim3(512), dim3(256), 0, stream>>>(QK, Vt, Ob);
  gemm_bt<64, true, false><<<dim3(64, 8), dim3(256), 0, stream>>>(
      Ob, Wyb, by, out, nullptr, MROWS, DM, DM, DM, 0, 1.0f);
}

// Round 7
// 88.697 us; speedup vs baseline: 2.0550x; 2.0550x over previous
//
#include <hip/hip_runtime.h>

#define DEV __device__ __forceinline__

typedef __attribute__((ext_vector_type(8))) short bf16x8;
typedef __attribute__((ext_vector_type(4))) float f32x4;
typedef __attribute__((ext_vector_type(16))) float f32x16;

// ---------- helpers ----------
DEV ushort f2bf(float f) {
  union { float f; unsigned u; } x; x.f = f;
  unsigned r = (x.u + 0x7FFFu + ((x.u >> 16) & 1u)) >> 16;
  return (ushort)r;
}

DEV void gload16(const void* g, void* l) {
  __builtin_amdgcn_global_load_lds(
      (const __attribute__((address_space(1))) void*)g,
      (__attribute__((address_space(3))) void*)l, 16, 0, 0);
}

DEV f32x4 mfma16(bf16x8 a, bf16x8 b, f32x4 c) {
  return __builtin_amdgcn_mfma_f32_16x16x32_bf16(a, b, c, 0, 0, 0);
}
DEV f32x16 mfma32(bf16x8 a, bf16x8 b, f32x16 c) {
  return __builtin_amdgcn_mfma_f32_32x32x16_bf16(a, b, c, 0, 0, 0);
}

DEV unsigned cvtpk(float a, float b) {
  unsigned r;
  asm("v_cvt_pk_bf16_f32 %0, %1, %2" : "=v"(r) : "v"(a), "v"(b));
  return r;
}

#if __has_builtin(__builtin_amdgcn_exp2f)
#define EXP2(x) __builtin_amdgcn_exp2f(x)
#else
#define EXP2(x) exp2f(x)
#endif

// ---------- sizes ----------
#define BB 2
#define SS 2048
#define HH 16
#define DD 64
#define DM 1024
#define MROWS (BB * SS)       // 4096
#define NQKV  (3 * DM)        // 3072
#define NQK   (2 * DM)        // 2048 (Q|K buffer stride)

// ---------- convert & pack f32 -> bf16 ----------
__global__ void convert_kernel(const float* __restrict__ hs,
                               const float* __restrict__ Wq, const float* __restrict__ bq,
                               const float* __restrict__ Wk, const float* __restrict__ bk,
                               const float* __restrict__ Wv, const float* __restrict__ bv,
                               const float* __restrict__ Wy,
                               ushort* __restrict__ Xb, ushort* __restrict__ Wqkv,
                               ushort* __restrict__ Wyb, float* __restrict__ bqkv) {
  const int HS_V = (MROWS * DM) / 4;     // 1048576
  const int WQ_V = (NQKV * DM) / 4;      // 786432
  const int WY_V = (DM * DM) / 4;        // 262144
  int idx = blockIdx.x * 256 + threadIdx.x;
  if (idx < HS_V) {
    float4 v = ((const float4*)hs)[idx];
    ushort4 o; o.x = f2bf(v.x); o.y = f2bf(v.y); o.z = f2bf(v.z); o.w = f2bf(v.w);
    ((ushort4*)Xb)[idx] = o;
  } else if (idx < HS_V + WQ_V) {
    int e = (idx - HS_V) * 4;
    int n = e >> 10, k = e & 1023;
    const float* W = (n < 1024) ? Wq : (n < 2048) ? Wk : Wv;
    int nn = n & 1023;
    float4 v = *(const float4*)(W + nn * 1024 + k);
    ushort4 o; o.x = f2bf(v.x); o.y = f2bf(v.y); o.z = f2bf(v.z); o.w = f2bf(v.w);
    ((ushort4*)Wqkv)[idx - HS_V] = o;
  } else if (idx < HS_V + WQ_V + WY_V) {
    int e = idx - HS_V - WQ_V;
    float4 v = ((const float4*)Wy)[e];
    ushort4 o; o.x = f2bf(v.x); o.y = f2bf(v.y); o.z = f2bf(v.z); o.w = f2bf(v.w);
    ((ushort4*)Wyb)[e] = o;
  }
  if (idx < NQKV)
    bqkv[idx] = (idx < 1024) ? bq[idx] : (idx < 2048) ? bk[idx - 1024] : bv[idx - 2048];
}

// ---------- GEMM (round-3 proven structure): BK=64, BM x 128 tile, 4 waves ----------
// C[m,n] = (sum_k A[m,k]*Bw[n,k] + bias[n]) * (n<scaleN ? qscale : 1)
// VSPLIT: n>=2048 quarter is written directly into Vt [b*16+h][d][s] (fused transpose).
template <int BM, bool OUT_F32, bool VSPLIT>
__global__ void gemm_bt(const ushort* __restrict__ A, const ushort* __restrict__ Bw,
                        const float* __restrict__ bias, void* __restrict__ Cout,
                        ushort* __restrict__ VtOut,
                        int M, int N, int K, int Nc, int scaleN, float qscale) {
  constexpr int NI = BM / 32;           // 16-row acc frags per wave (m dir)
  __shared__ ushort Al[BM * 64];
  __shared__ ushort Bl[128 * 64];
  const int tid = threadIdx.x;
  const int lane = tid & 63;
  const int wave = tid >> 6;
  const int lg = lane >> 4, l15 = lane & 15;
  const int m0 = blockIdx.x * BM, n0 = blockIdx.y * 128;
  const int wm = (wave >> 1) * (BM / 2), wn = (wave & 1) * 64;

  f32x4 acc[NI][4] = {};

  for (int k0 = 0; k0 < K; k0 += 64) {
    // stage A (BM x 64) and B (128 x 64), chunk-swizzled via global source
#pragma unroll
    for (int s = 0; s < BM * 8 / 256; ++s) {
      int f = tid + s * 256;
      int row = f >> 3, c = f & 7, cs = c ^ (row & 7);
      gload16(A + (size_t)(m0 + row) * K + k0 + cs * 8, (char*)Al + f * 16);
    }
#pragma unroll
    for (int s = 0; s < 4; ++s) {
      int f = tid + s * 256;
      int row = f >> 3, c = f & 7, cs = c ^ (row & 7);
      gload16(Bw + (size_t)(n0 + row) * K + k0 + cs * 8, (char*)Bl + f * 16);
    }
    __syncthreads();

#pragma unroll
    for (int kk = 0; kk < 2; ++kk) {
      bf16x8 af[NI], bfr[4];
#pragma unroll
      for (int i = 0; i < NI; ++i) {
        int rA = wm + i * 16 + l15;
        int cA = (kk * 4 + lg) ^ (rA & 7);
        af[i] = *(const bf16x8*)((const char*)Al + rA * 128 + cA * 16);
      }
#pragma unroll
      for (int j = 0; j < 4; ++j) {
        int rB = wn + j * 16 + l15;
        int cB = (kk * 4 + lg) ^ (rB & 7);
        bfr[j] = *(const bf16x8*)((const char*)Bl + rB * 128 + cB * 16);
      }
#pragma unroll
      for (int i = 0; i < NI; ++i)
#pragma unroll
        for (int j = 0; j < 4; ++j)
          acc[i][j] = mfma16(af[i], bfr[j], acc[i][j]);
    }
    __syncthreads();
  }

  // epilogue
  if (VSPLIT && n0 >= 2048) {
    // V quarter: write directly into Vt [b*16+h][d][s] (transpose fused)
#pragma unroll
    for (int i = 0; i < NI; ++i) {
#pragma unroll
      for (int j = 0; j < 4; ++j) {
        int n = n0 + wn + j * 16 + l15;
        float bv = bias[n];
        int h = (n >> 6) & 15, d = n & 63;
        int mb = m0 + wm + i * 16 + lg * 4;
        int b = mb >> 11, s = mb & 2047;
        ushort4 o;
        o.x = f2bf(acc[i][j][0] + bv);
        o.y = f2bf(acc[i][j][1] + bv);
        o.z = f2bf(acc[i][j][2] + bv);
        o.w = f2bf(acc[i][j][3] + bv);
        *(ushort4*)(VtOut + ((size_t)(b * 16 + h) * 64 + d) * SS + s) = o;
      }
    }
  } else {
#pragma unroll
    for (int i = 0; i < NI; ++i) {
#pragma unroll
      for (int j = 0; j < 4; ++j) {
        int n = n0 + wn + j * 16 + l15;
        float bv = bias[n];
        float qs = (n < scaleN) ? qscale : 1.0f;
#pragma unroll
        for (int r = 0; r < 4; ++r) {
          int m = m0 + wm + i * 16 + lg * 4 + r;
          float v = (acc[i][j][r] + bv) * qs;
          if (OUT_F32)
            ((float*)Cout)[(size_t)m * Nc + n] = v;
          else
            ((ushort*)Cout)[(size_t)m * Nc + n] = f2bf(v);
        }
      }
    }
  }
}

// ---------- flash attention: split-K groups + sequential qtile pairing ----------
// grid 512 x 256thr = 4 waves. QBLK=64 (waves 0/1 = q halves), groups {w0,w1},{w2,w3}
// process even/odd KV blocks (KVBLK=64) with private double-buffers; partials
// (o_acc, psum) merged via LDS (valid: reference softmax has no max-subtraction,
// so partials are pure sums). Qtile pair {x, 31-x} => every block ~17 iters flat.
__global__ __launch_bounds__(256, 2)
void attn_kernel(const ushort* __restrict__ QK, const ushort* __restrict__ Vt,
                 ushort* __restrict__ Ob) {
  __shared__ __align__(16) char SMEM[65536];

  const int tid = threadIdx.x;
  const int wave = tid >> 6, lane = tid & 63;
  const int l31 = lane & 31, hi = lane >> 5;
  const int grp = wave >> 1, wq = wave & 1;

  // XCD-locality swizzle: bh&7 == n&7 => each XCD sees 4 bh (KV fits L2)
  const int n = blockIdx.x;
  const int bh = (n & 7) | ((n >> 7) << 3);
  const int pairi = (n >> 3) & 15;
  const int b = bh >> 4, h = bh & 15;

  // probe v_permlane32_swap direction (wave-uniform)
  int px = lane, pw = 1000;
  asm volatile("v_permlane32_swap_b32 %0, %1" : "+v"(px), "+v"(pw));
  const bool defA = (__builtin_amdgcn_readfirstlane(px) == 0);

  const int gtid = tid & 127;
  const int srow = gtid >> 3;
  const int scs = (gtid & 7) ^ (srow & 7);
  const ushort* Kg = QK + (size_t)(b * SS + srow) * NQK + DM + h * 64 + scs * 8;
  const ushort* Vg = Vt + (size_t)(bh * 64 + srow) * SS + scs * 8;

#define STAGE(d_, kv0_) do {                                            \
    const ushort* kg_ = Kg + (size_t)(kv0_) * NQK;                      \
    const ushort* vg_ = Vg + (kv0_);                                    \
    char* kl_ = SMEM + (grp * 2 + (d_)) * 8192 + gtid * 16;             \
    char* vl_ = SMEM + 32768 + (grp * 2 + (d_)) * 8192 + gtid * 16;     \
    _Pragma("unroll")                                                   \
    for (int s_ = 0; s_ < 4; ++s_) {                                    \
      gload16(kg_ + (size_t)s_ * 16 * NQK, kl_ + s_ * 2048);            \
      gload16(vg_ + (size_t)s_ * 16 * SS,  vl_ + s_ * 2048);            \
    }                                                                   \
  } while (0)

  union U4 { unsigned u[4]; bf16x8 v; };

#define PACKH(sv, R, D0, D1, D2, D3) do {                              \
    unsigned X = cvtpk(sv[R + 0], sv[R + 1]);                          \
    unsigned Y = cvtpk(sv[R + 2], sv[R + 3]);                          \
    unsigned W = cvtpk(sv[R + 4], sv[R + 5]);                          \
    unsigned Z = cvtpk(sv[R + 6], sv[R + 7]);                          \
    if (defA) {                                                        \
      asm volatile("v_permlane32_swap_b32 %0, %1" : "+v"(X), "+v"(W)); \
      asm volatile("v_permlane32_swap_b32 %0, %1" : "+v"(Y), "+v"(Z)); \
    } else {                                                           \
      asm volatile("v_permlane32_swap_b32 %0, %1" : "+v"(W), "+v"(X)); \
      asm volatile("v_permlane32_swap_b32 %0, %1" : "+v"(Z), "+v"(Y)); \
    }                                                                  \
    D0 = X; D1 = Y; D2 = W; D3 = Z;                                    \
  } while (0)

#pragma unroll 1
  for (int ph = 0; ph < 2; ++ph) {
    __builtin_amdgcn_s_barrier();  // protects merge area of previous phase

    const int qt = ph ? (31 - pairi) : pairi;
    const int q0 = qt * 64;
    const int nkv = qt + 1;
    const int niter = (nkv + 1) >> 1;
    const int qw = q0 + wq * 32;
    const int q_lane = qw + l31;

    const ushort* Qrow = QK + (size_t)(b * SS + q_lane) * NQK + h * 64 + hi * 8;
    bf16x8 qf0 = *(const bf16x8*)(Qrow);
    bf16x8 qf1 = *(const bf16x8*)(Qrow + 16);
    bf16x8 qf2 = *(const bf16x8*)(Qrow + 32);
    bf16x8 qf3 = *(const bf16x8*)(Qrow + 48);

    f32x16 acc0 = {}, acc1 = {};
    float ps0 = 0.f, ps1 = 0.f, ps2 = 0.f, ps3 = 0.f;

    if (grp < nkv) STAGE(0, grp * 64);
    int buf = 0;

#pragma unroll 1
    for (int it = 0; it < niter; ++it) {
      const int j = 2 * it + grp;
      if (j + 2 < nkv) {
        STAGE(buf ^ 1, (j + 2) * 64);
        asm volatile("s_waitcnt vmcnt(8)" ::: "memory");
      } else {
        asm volatile("s_waitcnt vmcnt(0)" ::: "memory");
      }
      __builtin_amdgcn_s_barrier();
      __builtin_amdgcn_sched_barrier(0);

      if (j < nkv) {
        const int kv0 = j * 64;
        const char* Kb = SMEM + (grp * 2 + buf) * 8192;
        const char* Vb = SMEM + 32768 + (grp * 2 + buf) * 8192;

        f32x16 s0 = {}, s1 = {};
        __builtin_amdgcn_s_setprio(1);
#pragma unroll
        for (int ks = 0; ks < 4; ++ks) {
          const int ch = (((ks * 2 + hi) ^ (l31 & 7)) * 16);
          bf16x8 kfa = *(const bf16x8*)(Kb + l31 * 128 + ch);
          bf16x8 kfb = *(const bf16x8*)(Kb + (l31 + 32) * 128 + ch);
          bf16x8 qk = (ks == 0) ? qf0 : (ks == 1) ? qf1 : (ks == 2) ? qf2 : qf3;
          s0 = mfma32(kfa, qk, s0);
          s1 = mfma32(kfb, qk, s1);
        }
        __builtin_amdgcn_s_setprio(0);

        if (j == qt) {
#pragma unroll
          for (int r = 0; r < 16; ++r) {
            const int tb = (r & 3) + 8 * (r >> 2) + 4 * hi;
            if (kv0 + tb > q_lane) s0[r] = -1e30f;
            if (kv0 + 32 + tb > q_lane) s1[r] = -1e30f;
          }
        }

#pragma unroll
        for (int r = 0; r < 16; r += 4) {
          float a0 = EXP2(s0[r]), a1 = EXP2(s0[r + 1]), a2 = EXP2(s0[r + 2]), a3 = EXP2(s0[r + 3]);
          s0[r] = a0; s0[r + 1] = a1; s0[r + 2] = a2; s0[r + 3] = a3;
          ps0 += a0; ps1 += a1; ps2 += a2; ps3 += a3;
          float b0 = EXP2(s1[r]), b1 = EXP2(s1[r + 1]), b2 = EXP2(s1[r + 2]), b3 = EXP2(s1[r + 3]);
          s1[r] = b0; s1[r + 1] = b1; s1[r + 2] = b2; s1[r + 3] = b3;
          ps0 += b0; ps1 += b1; ps2 += b2; ps3 += b3;
        }

        U4 f0, f1, f2, f3;
        PACKH(s0, 0, f0.u[0], f0.u[1], f0.u[2], f0.u[3]);
        PACKH(s0, 8, f1.u[0], f1.u[1], f1.u[2], f1.u[3]);
        PACKH(s1, 0, f2.u[0], f2.u[1], f2.u[2], f2.u[3]);
        PACKH(s1, 8, f3.u[0], f3.u[1], f3.u[2], f3.u[3]);

        __builtin_amdgcn_s_setprio(1);
#pragma unroll
        for (int ts = 0; ts < 4; ++ts) {
          const int ch = (((ts * 2 + hi) ^ (l31 & 7)) * 16);
          bf16x8 vfa = *(const bf16x8*)(Vb + l31 * 128 + ch);
          bf16x8 vfb = *(const bf16x8*)(Vb + (l31 + 32) * 128 + ch);
          bf16x8 pf = (ts == 0) ? f0.v : (ts == 1) ? f1.v : (ts == 2) ? f2.v : f3.v;
          acc0 = mfma32(vfa, pf, acc0);
          acc1 = mfma32(vfb, pf, acc1);
        }
        __builtin_amdgcn_s_setprio(0);
      }
      __builtin_amdgcn_sched_barrier(0);
      __builtin_amdgcn_s_barrier();
      buf ^= 1;
    }

    // ---- merge group partials (pure sums; no rescale needed) ----
    float psum = ps0 + ps1 + ps2 + ps3;
    f32x4* MA = (f32x4*)SMEM;            // [8][128]
    float* MP = (float*)(SMEM + 32768);  // [128]
    const int slot = wq * 64 + lane;
    if (grp == 1) {
#pragma unroll
      for (int c = 0; c < 4; ++c) {
        f32x4 t0 = {acc0[4 * c], acc0[4 * c + 1], acc0[4 * c + 2], acc0[4 * c + 3]};
        MA[c * 128 + slot] = t0;
        f32x4 t1 = {acc1[4 * c], acc1[4 * c + 1], acc1[4 * c + 2], acc1[4 * c + 3]};
        MA[(c + 4) * 128 + slot] = t1;
      }
      MP[slot] = psum;
    }
    __builtin_amdgcn_s_barrier();
    if (grp == 0) {
#pragma unroll
      for (int c = 0; c < 4; ++c) {
        f32x4 t0 = MA[c * 128 + slot];
        f32x4 t1 = MA[(c + 4) * 128 + slot];
        acc0[4 * c] += t0[0]; acc0[4 * c + 1] += t0[1];
        acc0[4 * c + 2] += t0[2]; acc0[4 * c + 3] += t0[3];
        acc1[4 * c] += t1[0]; acc1[4 * c + 1] += t1[1];
        acc1[4 * c + 2] += t1[2]; acc1[4 * c + 3] += t1[3];
      }
      psum += MP[slot];
      float tot = psum + __shfl_xor(psum, 32, 64);
      float inv = 1.0f / tot;
      ushort* orow = Ob + (size_t)(b * SS + q_lane) * DM + h * 64;
#pragma unroll
      for (int g = 0; g < 4; ++g) {
        uint2 st;
        st.x = cvtpk(acc0[4 * g + 0] * inv, acc0[4 * g + 1] * inv);
        st.y = cvtpk(acc0[4 * g + 2] * inv, acc0[4 * g + 3] * inv);
        *(uint2*)(orow + 8 * g + 4 * hi) = st;
        uint2 st2;
        st2.x = cvtpk(acc1[4 * g + 0] * inv, acc1[4 * g + 1] * inv);
        st2.y = cvtpk(acc1[4 * g + 2] * inv, acc1[4 * g + 3] * inv);
        *(uint2*)(orow + 32 + 8 * g + 4 * hi) = st2;
      }
    }
  }
#undef STAGE
#undef PACKH
}

// ---------- launch ----------
extern "C" void kernel_launch(void* const* d_in, const int* in_sizes, int n_in,
                              void* d_out, int out_size, void* d_ws, size_t ws_size,
                              hipStream_t stream) {
  const float* hs = (const float*)d_in[0];
  const float* Wq = (const float*)d_in[1];
  const float* bq = (const float*)d_in[2];
  const float* Wk = (const float*)d_in[3];
  const float* bk = (const float*)d_in[4];
  const float* Wv = (const float*)d_in[5];
  const float* bv = (const float*)d_in[6];
  const float* Wy = (const float*)d_in[7];
  const float* by = (const float*)d_in[8];
  float* out = (float*)d_out;

  char* ws = (char*)d_ws;
  ushort* Xb   = (ushort*)(ws);                          // 8 MiB  [4096][1024]
  ushort* Wqkv = (ushort*)(ws + (8ull  << 20));          // 6 MiB  [3072][1024]
  ushort* Wyb  = (ushort*)(ws + (14ull << 20));          // 2 MiB  [1024][1024]
  float*  bqkv = (float*) (ws + (16ull << 20));          // 12 KiB
  ushort* QK   = (ushort*)(ws + (17ull << 20));          // 16 MiB [4096][2048]
  ushort* Vt   = (ushort*)(ws + (33ull << 20));          // 8 MiB  [32][64][2048]
  ushort* Ob   = (ushort*)(ws + (41ull << 20));          // 8 MiB  [4096][1024]

  const float QSC = 0.125f * 1.44269504088896f;  // 1/sqrt(D) * log2(e)

  convert_kernel<<<dim3(8192), dim3(256), 0, stream>>>(hs, Wq, bq, Wk, bk, Wv, bv, Wy,
                                                       Xb, Wqkv, Wyb, bqkv);
  // QKV projection: Q|K -> QK buffer (stride 2048), V -> Vt (transpose fused)
  gemm_bt<128, false, true><<<dim3(32, 24), dim3(256), 0, stream>>>(
      Xb, Wqkv, bqkv, QK, Vt, MROWS, NQKV, DM, NQK, 1024, QSC);
  attn_kernel<<<dim3(512), dim3(256), 0, stream>>>(QK, Vt, Ob);
  gemm_bt<64, true, false><<<dim3(64, 8), dim3(256), 0, stream>>>(
      Ob, Wyb, by, out, nullptr, MROWS, DM, DM, DM, 0, 1.0f);
}